// Round 8
// baseline (436.188 us; speedup 1.0000x reference)
//
#include <hip/hip_runtime.h>

typedef __attribute__((ext_vector_type(8))) short short8;
typedef __attribute__((ext_vector_type(4))) float floatx4;

#define CSC 0.1803368801f   // 0.125 * log2(e): folded score scale + exp2 base change

__device__ __forceinline__ unsigned short f2b(float f){
  unsigned int u = __builtin_bit_cast(unsigned int, f);
  unsigned int r = (u + 0x7fffu + ((u >> 16) & 1u)) >> 16;
  return (unsigned short)r;
}
__device__ __forceinline__ float b2f(unsigned short h){
  unsigned int u = ((unsigned int)h) << 16;
  return __builtin_bit_cast(float, u);
}
__device__ __forceinline__ floatx4 mfma16(short8 a, short8 b, floatx4 c){
  return __builtin_amdgcn_mfma_f32_16x16x32_bf16(a, b, c, 0, 0, 0);
}

// ---------------------------------------------------------------------------
// Kernel 1: transpose + convert the three 768x768 S-weights to bf16, [n][k]
// ---------------------------------------------------------------------------
__global__ __launch_bounds__(256) void transpose_w(
    const float* __restrict__ Wq, const float* __restrict__ Wk,
    const float* __restrict__ Wv, unsigned short* __restrict__ Wb){
  __shared__ float tile[64][65];
  int g = blockIdx.z;
  const float* W = (g==0) ? Wq : (g==1) ? Wk : Wv;
  int r0 = blockIdx.y*64, c0 = blockIdx.x*64;
  int tx = threadIdx.x & 63, ty = threadIdx.x >> 6;
  #pragma unroll
  for (int i=0;i<16;i++){
    int r = i*4 + ty;
    tile[r][tx] = W[(r0+r)*768 + c0 + tx];
  }
  __syncthreads();
  unsigned short* dst = Wb + g*589824;
  #pragma unroll
  for (int i=0;i<16;i++){
    int rr = i*4 + ty;
    dst[(c0+rr)*768 + r0 + tx] = f2b(tile[tx][rr]);
  }
}

// ---------------------------------------------------------------------------
// Kernel 2: bf16 conversions (patches, Er) + time projections.
// Tmat[g][b][n]; g==0 slice pre-scaled by CSC (consumed by attn as Tq).
// ---------------------------------------------------------------------------
__global__ __launch_bounds__(256) void convert_kernel(
    const float* __restrict__ patches, const float* __restrict__ Er,
    const float* __restrict__ temb,
    const float* __restrict__ Wqt, const float* __restrict__ bqt,
    const float* __restrict__ Wkt, const float* __restrict__ bkt,
    const float* __restrict__ Wvt, const float* __restrict__ bvt,
    unsigned short* __restrict__ Pb, unsigned short* __restrict__ Erb,
    float* __restrict__ Tmat){
  int blk = blockIdx.x, tid = threadIdx.x;
  if (blk < 3104){
    const float* src; unsigned short* dst; int idx;
    if (blk < 3072){ idx = blk*2048 + tid*8; src = patches; dst = Pb; }
    else           { idx = (blk-3072)*2048 + tid*8; src = Er; dst = Erb; }
    float4 f0 = *(const float4*)(src + idx);
    float4 f1 = *(const float4*)(src + idx + 4);
    uint4 pk;
    pk.x = (unsigned)f2b(f0.x) | ((unsigned)f2b(f0.y)<<16);
    pk.y = (unsigned)f2b(f0.z) | ((unsigned)f2b(f0.w)<<16);
    pk.z = (unsigned)f2b(f1.x) | ((unsigned)f2b(f1.y)<<16);
    pk.w = (unsigned)f2b(f1.z) | ((unsigned)f2b(f1.w)<<16);
    *(uint4*)(dst + idx) = pk;
  } else {
    int g = (blk-3104)>>3, bb = (blk-3104)&7;
    const float* Wt = (g==0)? Wqt : (g==1)? Wkt : Wvt;
    const float* bt = (g==0)? bqt : (g==1)? bkt : bvt;
    __shared__ float emb[384];
    for (int j=tid;j<384;j+=256) emb[j] = temb[bb*384 + j];
    __syncthreads();
    float acc0 = bt[tid], acc1 = bt[tid+256], acc2 = bt[tid+512];
    for (int t=0;t<384;t++){
      float e = emb[t];
      const float* wr = Wt + t*768;
      acc0 += e*wr[tid]; acc1 += e*wr[tid+256]; acc2 += e*wr[tid+512];
    }
    float* dst = Tmat + g*6144 + bb*768;
    float s = (g==0) ? CSC : 1.0f;
    dst[tid] = acc0*s; dst[tid+256] = acc1*s; dst[tid+512] = acc2*s;
  }
}

// ---------------------------------------------------------------------------
// Kernel 3: fused QKV GEMM (A = bf16 patches). Writes:
//   Qs[b][h][s][hd] = (patches@Wqs + bqs) * CSC     (bf16, pre-scaled)
//   K [b][h][s][hd] = ks + kt                        (bf16)
//   V  transposed per head [b][h][hd][s]             (bf16)
// V epilogue routes through LDS so global stores are coalesced 256B runs.
// ---------------------------------------------------------------------------
__global__ __launch_bounds__(256) void qkv_gemm(
    const unsigned short* __restrict__ Pb, const unsigned short* __restrict__ Wb,
    const float* __restrict__ bq, const float* __restrict__ bk,
    const float* __restrict__ bv, const float* __restrict__ Tmat,
    unsigned short* __restrict__ Qs, unsigned short* __restrict__ K,
    unsigned short* __restrict__ V){
  __shared__ unsigned short smem_q[18432];       // a:0..9215, b:9216..18431
  unsigned short* a_lds = smem_q;
  unsigned short* b_lds = smem_q + 9216;
  int g = blockIdx.z;
  int m0 = blockIdx.x*128, n0 = blockIdx.y*128;
  int tid = threadIdx.x, w = tid>>6, lane = tid&63, quad = lane>>4, l16 = lane&15;
  int wr = w>>1, wc = w&1;
  const unsigned short* Wg = Wb + g*589824;
  const float* bias = (g==0)? bq : (g==1)? bk : bv;
  floatx4 acc[4][4];
  #pragma unroll
  for (int i=0;i<4;i++)
    #pragma unroll
    for (int j=0;j<4;j++) acc[i][j] = (floatx4){0.f,0.f,0.f,0.f};

  for (int kt=0; kt<12; kt++){
    int k0 = kt*64;
    __syncthreads();
    #pragma unroll
    for (int i=0;i<4;i++){
      int idx = i*256 + tid;
      int r = idx >> 3, c = (idx & 7) << 3;
      *(uint4*)&a_lds[r*72 + c] = *(const uint4*)&Pb[(m0+r)*768 + k0 + c];
      *(uint4*)&b_lds[r*72 + c] = *(const uint4*)&Wg[(n0+r)*768 + k0 + c];
    }
    __syncthreads();
    #pragma unroll
    for (int ks=0; ks<2; ks++){
      short8 af[4], bf[4];
      #pragma unroll
      for (int mb=0;mb<4;mb++)
        af[mb] = *(const short8*)&a_lds[(wr*64+mb*16+l16)*72 + ks*32 + quad*8];
      #pragma unroll
      for (int nb=0;nb<4;nb++)
        bf[nb] = *(const short8*)&b_lds[(wc*64+nb*16+l16)*72 + ks*32 + quad*8];
      #pragma unroll
      for (int mb=0;mb<4;mb++)
        #pragma unroll
        for (int nb=0;nb<4;nb++)
          acc[mb][nb] = mfma16(af[mb], bf[nb], acc[mb][nb]);
    }
  }
  if (g < 2){
    #pragma unroll
    for (int mb=0;mb<4;mb++)
    #pragma unroll
    for (int nb=0;nb<4;nb++)
    #pragma unroll
    for (int reg=0;reg<4;reg++){
      int m = m0 + wr*64 + mb*16 + quad*4 + reg;
      int n = n0 + wc*64 + nb*16 + l16;
      int bb = m >> 10, s = m & 1023, h = n >> 6, hd = n & 63;
      float v = acc[mb][nb][reg] + bias[n];
      int base = (bb*12 + h) << 16;
      if (g == 0){
        Qs[base + (s<<6) + hd] = f2b(v * CSC);
      } else {
        float tadd = Tmat[6144 + bb*768 + n];
        K[base + (s<<6) + hd] = f2b(v + tadd);
      }
    }
  } else {
    // V: write C-tile transposed into LDS (stride 136), then coalesced store
    __syncthreads();     // main-loop LDS reads complete
    int bb = m0 >> 10;
    #pragma unroll
    for (int mb=0;mb<4;mb++)
    #pragma unroll
    for (int nb=0;nb<4;nb++)
    #pragma unroll
    for (int reg=0;reg<4;reg++){
      int ml = wr*64 + mb*16 + quad*4 + reg;
      int nl = wc*64 + nb*16 + l16;
      int n = n0 + nl;
      float v = acc[mb][nb][reg] + bias[n] + Tmat[12288 + bb*768 + n];
      smem_q[nl*136 + ml] = f2b(v);
    }
    __syncthreads();
    int s0 = m0 & 1023;
    #pragma unroll
    for (int i=0;i<8;i++){
      int idx = i*256 + tid;
      int r = idx >> 4, c8 = (idx & 15) << 3;   // r: n_local, c8: m_local
      int n = n0 + r, h = n >> 6, hd = n & 63;
      int base = (bb*12 + h) << 16;
      *(uint4*)&V[base + (hd<<10) + s0 + c8] = *(const uint4*)&smem_q[r*136 + c8];
    }
  }
}

// ---------------------------------------------------------------------------
// Kernel 4: flash attention w/ skewed relative bias.  DS-DIET edition.
// Block = 256 threads (4 waves), q-PAIR (sub A=q0, B=q0+64) per k-tile.
// Grid 768 = 3 blocks/CU, single round. K/V register-prefetch pipeline.
// The kernel is LDS-pipe-bound (R7 analysis): per-CU DS cycles == wall time.
// Cuts vs R5: (1) band region col-major bf16 stride 20 -> writes are
// 5 x ds_write_b64/pass (was 20 x u16), conflict-free; (2) separate P0/P1
// regions so V fragments are read ONCE per iter (was twice).
// LDS = 9216 + 9216 + 4*(3200 + 2*2304) = 49664 B -> 3 blocks/CU.
// ---------------------------------------------------------------------------
__global__ __launch_bounds__(256, 3) void attn_kernel(
    const unsigned short* __restrict__ Qsp, const unsigned short* __restrict__ Kp,
    const unsigned short* __restrict__ Vtp, const unsigned short* __restrict__ Erb,
    const float* __restrict__ Tq, float* __restrict__ out){
  __shared__ __align__(16) char smem[49664];
  unsigned short* k_lds = (unsigned short*)smem;             // 64x72
  unsigned short* v_lds = (unsigned short*)(smem + 9216);    // 64x72 (vT [hd][key])
  unsigned short* wbase = (unsigned short*)(smem + 18432);   // 4 x 3904 u16

  int tid = threadIdx.x, w = tid>>6, lane = tid&63, quad = lane>>4, l16 = lane&15;
  unsigned short* bandw = wbase + w*3904;      // 80 cols x 16 rows, stride 20 (col-major)
  unsigned short* p_l0  = bandw + 1600;        // 16x72
  unsigned short* p_l1  = bandw + 2752;        // 16x72
  int q0 = blockIdx.x*128, h = blockIdx.y, b = blockIdx.z;
  int hb = (b*12 + h) << 16;
  const unsigned short* Qsh = Qsp + hb;
  const unsigned short* Kh  = Kp  + hb;
  const unsigned short* Vh  = Vtp + hb;
  const float* tqv = Tq + b*768 + h*64;    // pre-scaled by CSC

  int frow = w*16 + l16;
  short8 qf[2][2], qlo[2][2], qhi[2][2];   // [sub][ks]
  #pragma unroll
  for (int sub=0; sub<2; sub++){
    int qrow = q0 + sub*64 + frow;
    int qrow1 = (qrow < 1023) ? qrow+1 : 1023;
    #pragma unroll
    for (int ks=0; ks<2; ks++){
      int c = ks*32 + quad*8;
      qlo[sub][ks] = *(const short8*)&Qsh[(qrow <<6) + c];
      qhi[sub][ks] = *(const short8*)&Qsh[(qrow1<<6) + c];
      float4 t0 = *(const float4*)&tqv[c];
      float4 t1 = *(const float4*)&tqv[c+4];
      short8 qq;
      qq[0]=(short)f2b(b2f((unsigned short)qlo[sub][ks][0])+t0.x);
      qq[1]=(short)f2b(b2f((unsigned short)qlo[sub][ks][1])+t0.y);
      qq[2]=(short)f2b(b2f((unsigned short)qlo[sub][ks][2])+t0.z);
      qq[3]=(short)f2b(b2f((unsigned short)qlo[sub][ks][3])+t0.w);
      qq[4]=(short)f2b(b2f((unsigned short)qlo[sub][ks][4])+t1.x);
      qq[5]=(short)f2b(b2f((unsigned short)qlo[sub][ks][5])+t1.y);
      qq[6]=(short)f2b(b2f((unsigned short)qlo[sub][ks][6])+t1.z);
      qq[7]=(short)f2b(b2f((unsigned short)qlo[sub][ks][7])+t1.w);
      qf[sub][ks] = qq;
    }
  }

  float lpart[2][4] = {{0.f,0.f,0.f,0.f},{0.f,0.f,0.f,0.f}};
  floatx4 o_acc[2][4];
  #pragma unroll
  for (int sub=0;sub<2;sub++)
    #pragma unroll
    for (int ob=0;ob<4;ob++) o_acc[sub][ob] = (floatx4){0.f,0.f,0.f,0.f};

  int ql = quad*4;           // + reg = within-wave q row
  int ub_lo = 3 - w;         // wave-w band blocks [3-w, 7-w]

  // K/V staging addressing: thread covers rows sr, sr+32 (col chunk scc)
  int sr = tid>>3, scc = (tid&7)<<3;
  uint4 kr0, kr1, vr0, vr1;
  kr0 = *(const uint4*)&Kh[(sr<<6) + scc];
  kr1 = *(const uint4*)&Kh[((sr+32)<<6) + scc];
  vr0 = *(const uint4*)&Vh[(sr<<10) + scc];
  vr1 = *(const uint4*)&Vh[((sr+32)<<10) + scc];

  for (int kt=0; kt<16; kt++){
    int k0 = kt*64;
    __syncthreads();                       // all waves done reading k/v
    *(uint4*)&k_lds[sr*72 + scc]      = kr0;
    *(uint4*)&k_lds[(sr+32)*72 + scc] = kr1;
    *(uint4*)&v_lds[sr*72 + scc]      = vr0;
    *(uint4*)&v_lds[(sr+32)*72 + scc] = vr1;
    __syncthreads();
    // prefetch next k-tile (clamped re-load of tile 15 on last iter)
    int k0n = (kt < 15) ? k0 + 64 : k0;
    kr0 = *(const uint4*)&Kh[((k0n+sr)<<6) + scc];
    kr1 = *(const uint4*)&Kh[((k0n+sr+32)<<6) + scc];
    vr0 = *(const uint4*)&Vh[(sr<<10) + k0n + scc];
    vr1 = *(const uint4*)&Vh[((sr+32)<<10) + k0n + scc];

    // ---- QK^T for both sub-tiles, sharing kf fragment reads ----
    floatx4 sc[2][4];
    #pragma unroll
    for (int nb=0;nb<4;nb++){
      sc[0][nb] = (floatx4){0.f,0.f,0.f,0.f};
      sc[1][nb] = (floatx4){0.f,0.f,0.f,0.f};
      #pragma unroll
      for (int ks=0;ks<2;ks++){
        short8 kf = *(const short8*)&k_lds[(nb*16+l16)*72 + ks*32 + quad*8];
        sc[0][nb] = mfma16(qf[0][ks], kf, sc[0][nb]);
        sc[1][nb] = mfma16(qf[1][ks], kf, sc[1][nb]);
      }
    }

    #pragma unroll
    for (int sub=0; sub<2; sub++){
      int diag = k0 - q0 - sub*64;
      bool needL = (diag <= 0), needU = (diag >= 0);
      bool needSel = (diag == 0) || (diag == 64);
      for (int pass=0; pass<2; pass++){
        if ((pass==0 && !needL) || (pass==1 && !needU)) continue;
        int tbase = (pass==0) ? (960 + diag) : (diag - 65);
        const short8* af = (pass==0) ? qlo[sub] : qhi[sub];
        // band GEMM: 5 ub blocks per wave, Er B-frags direct from global;
        // output packed to bf16 and stored col-major (stride 20) as b64
        #pragma unroll
        for (int lb=0; lb<5; lb++){
          int ub = ub_lo + lb;
          int t = tbase + ub*16 + l16;
          t = (t < 0) ? 0 : (t > 1023 ? 1023 : t);
          floatx4 pa = (floatx4){0.f,0.f,0.f,0.f};
          #pragma unroll
          for (int ks=0;ks<2;ks++){
            short8 ef = *(const short8*)&Erb[(t<<6) + ks*32 + quad*8];
            pa = mfma16(af[ks], ef, pa);
          }
          uint2 pk;
          pk.x = (unsigned)f2b(pa[0]) | ((unsigned)f2b(pa[1])<<16);
          pk.y = (unsigned)f2b(pa[2]) | ((unsigned)f2b(pa[3])<<16);
          *(uint2*)&bandw[(lb*16 + l16)*20 + ql] = pk;   // rows ql..ql+3
        }
        // gather-add (wave-private; in-wave DS ordering); col-major read
        #pragma unroll
        for (int nb=0;nb<4;nb++)
        #pragma unroll
        for (int reg=0;reg<4;reg++){
          int qlr = ql + reg;
          int ki = nb*16 + l16;
          float bv = b2f(bandw[(15 + ki - qlr)*20 + qlr]);
          if (needSel){
            int kq = diag + ki - (w*16 + qlr);
            bool sel = (pass==0) ? (kq <= 0) : (kq >= 2);
            bv = sel ? bv : 0.f;
          }
          sc[sub][nb][reg] += bv;
        }
      }
      // ---- fixed-base softmax: p = 2^sc (scale folded into Q/Qs) ----
      unsigned short* p_lds = (sub==0) ? p_l0 : p_l1;
      #pragma unroll
      for (int nb=0;nb<4;nb++)
      #pragma unroll
      for (int reg=0;reg<4;reg++){
        float p = __builtin_amdgcn_exp2f(sc[sub][nb][reg]);
        lpart[sub][reg] += p;
        p_lds[(ql + reg)*72 + nb*16 + l16] = f2b(p);
      }
    }
    // ---- PV for both subs, V fragments read once ----
    short8 pf0[2], pf1[2];
    #pragma unroll
    for (int ks=0;ks<2;ks++){
      pf0[ks] = *(const short8*)&p_l0[l16*72 + ks*32 + quad*8];
      pf1[ks] = *(const short8*)&p_l1[l16*72 + ks*32 + quad*8];
    }
    #pragma unroll
    for (int ob=0;ob<4;ob++){
      #pragma unroll
      for (int ks=0;ks<2;ks++){
        short8 vf = *(const short8*)&v_lds[(ob*16+l16)*72 + ks*32 + quad*8];
        o_acc[0][ob] = mfma16(pf0[ks], vf, o_acc[0][ob]);
        o_acc[1][ob] = mfma16(pf1[ks], vf, o_acc[1][ob]);
      }
    }
  }
  // final row-sum reduce (deferred; no per-tile rescale happened)
  #pragma unroll
  for (int sub=0;sub<2;sub++){
    float rl[4];
    #pragma unroll
    for (int reg=0;reg<4;reg++){
      float l = lpart[sub][reg];
      #pragma unroll
      for (int off=1; off<16; off<<=1) l += __shfl_xor(l, off);
      rl[reg] = __builtin_amdgcn_rcpf(l);
    }
    #pragma unroll
    for (int ob=0;ob<4;ob++)
    #pragma unroll
    for (int reg=0;reg<4;reg++){
      int s = q0 + sub*64 + w*16 + quad*4 + reg;
      out[((b<<10) + s)*768 + (h<<6) + ob*16 + l16] = o_acc[sub][ob][reg] * rl[reg];
    }
  }
}

// ---------------------------------------------------------------------------
extern "C" void kernel_launch(void* const* d_in, const int* in_sizes, int n_in,
                              void* d_out, int out_size, void* d_ws, size_t ws_size,
                              hipStream_t stream) {
  const float* patches  = (const float*)d_in[0];
  const float* time_emb = (const float*)d_in[1];
  const float* Wqs = (const float*)d_in[2];  const float* bqs = (const float*)d_in[3];
  const float* Wks = (const float*)d_in[4];  const float* bks = (const float*)d_in[5];
  const float* Wvs = (const float*)d_in[6];  const float* bvs = (const float*)d_in[7];
  const float* Wqt = (const float*)d_in[8];  const float* bqt = (const float*)d_in[9];
  const float* Wkt = (const float*)d_in[10]; const float* bkt = (const float*)d_in[11];
  const float* Wvt = (const float*)d_in[12]; const float* bvt = (const float*)d_in[13];
  const float* Er  = (const float*)d_in[14];

  unsigned short* Qsp  = (unsigned short*)d_ws;     // 6291456 (bf16, pre-scaled)
  unsigned short* Kp   = Qsp + 6291456;
  unsigned short* Vp   = Kp  + 6291456;             // transposed per head [hd][s]
  unsigned short* Wbp  = Vp  + 6291456;             // 3*589824, [g][n][k]
  unsigned short* Erbp = Wbp + 1769472;             // 65536
  unsigned short* Pbp  = Erbp + 65536;              // 6291456 (patches bf16)
  float*          Tmat = (float*)(Pbp + 6291456);   // 3*8*768 fp32 (g0 * CSC)

  float* out = (float*)d_out;

  hipLaunchKernelGGL(convert_kernel, dim3(3128), dim3(256), 0, stream,
                     patches, Er, time_emb, Wqt, bqt, Wkt, bkt, Wvt, bvt,
                     Pbp, Erbp, Tmat);
  hipLaunchKernelGGL(transpose_w, dim3(12,12,3), dim3(256), 0, stream,
                     Wqs, Wks, Wvs, Wbp);
  hipLaunchKernelGGL(qkv_gemm, dim3(64,6,3), dim3(256), 0, stream,
                     Pbp, Wbp, bqs, bks, bvs, Tmat, Qsp, Kp, Vp);
  hipLaunchKernelGGL(attn_kernel, dim3(8,12,8), dim3(256), 0, stream,
                     Qsp, Kp, Vp, Erbp, Tmat, out);
}

// Round 9
// 332.243 us; speedup vs baseline: 1.3129x; 1.3129x over previous
//
#include <hip/hip_runtime.h>

typedef __attribute__((ext_vector_type(8))) short short8;
typedef __attribute__((ext_vector_type(4))) float floatx4;

#define CSC 0.1803368801f   // 0.125 * log2(e): folded score scale + exp2 base change

__device__ __forceinline__ unsigned short f2b(float f){
  unsigned int u = __builtin_bit_cast(unsigned int, f);
  unsigned int r = (u + 0x7fffu + ((u >> 16) & 1u)) >> 16;
  return (unsigned short)r;
}
__device__ __forceinline__ float b2f(unsigned short h){
  unsigned int u = ((unsigned int)h) << 16;
  return __builtin_bit_cast(float, u);
}
__device__ __forceinline__ floatx4 mfma16(short8 a, short8 b, floatx4 c){
  return __builtin_amdgcn_mfma_f32_16x16x32_bf16(a, b, c, 0, 0, 0);
}

// ---------------------------------------------------------------------------
// Kernel 1: transpose + convert the three 768x768 S-weights to bf16, [n][k]
// ---------------------------------------------------------------------------
__global__ __launch_bounds__(256) void transpose_w(
    const float* __restrict__ Wq, const float* __restrict__ Wk,
    const float* __restrict__ Wv, unsigned short* __restrict__ Wb){
  __shared__ float tile[64][65];
  int g = blockIdx.z;
  const float* W = (g==0) ? Wq : (g==1) ? Wk : Wv;
  int r0 = blockIdx.y*64, c0 = blockIdx.x*64;
  int tx = threadIdx.x & 63, ty = threadIdx.x >> 6;
  #pragma unroll
  for (int i=0;i<16;i++){
    int r = i*4 + ty;
    tile[r][tx] = W[(r0+r)*768 + c0 + tx];
  }
  __syncthreads();
  unsigned short* dst = Wb + g*589824;
  #pragma unroll
  for (int i=0;i<16;i++){
    int rr = i*4 + ty;
    dst[(c0+rr)*768 + r0 + tx] = f2b(tile[tx][rr]);
  }
}

// ---------------------------------------------------------------------------
// Kernel 2: bf16 conversions (patches, Er) + time projections.
// Tmat[g][b][n]; g==0 slice pre-scaled by CSC (consumed by attn as Tq).
// ---------------------------------------------------------------------------
__global__ __launch_bounds__(256) void convert_kernel(
    const float* __restrict__ patches, const float* __restrict__ Er,
    const float* __restrict__ temb,
    const float* __restrict__ Wqt, const float* __restrict__ bqt,
    const float* __restrict__ Wkt, const float* __restrict__ bkt,
    const float* __restrict__ Wvt, const float* __restrict__ bvt,
    unsigned short* __restrict__ Pb, unsigned short* __restrict__ Erb,
    float* __restrict__ Tmat){
  int blk = blockIdx.x, tid = threadIdx.x;
  if (blk < 3104){
    const float* src; unsigned short* dst; int idx;
    if (blk < 3072){ idx = blk*2048 + tid*8; src = patches; dst = Pb; }
    else           { idx = (blk-3072)*2048 + tid*8; src = Er; dst = Erb; }
    float4 f0 = *(const float4*)(src + idx);
    float4 f1 = *(const float4*)(src + idx + 4);
    uint4 pk;
    pk.x = (unsigned)f2b(f0.x) | ((unsigned)f2b(f0.y)<<16);
    pk.y = (unsigned)f2b(f0.z) | ((unsigned)f2b(f0.w)<<16);
    pk.z = (unsigned)f2b(f1.x) | ((unsigned)f2b(f1.y)<<16);
    pk.w = (unsigned)f2b(f1.z) | ((unsigned)f2b(f1.w)<<16);
    *(uint4*)(dst + idx) = pk;
  } else {
    int g = (blk-3104)>>3, bb = (blk-3104)&7;
    const float* Wt = (g==0)? Wqt : (g==1)? Wkt : Wvt;
    const float* bt = (g==0)? bqt : (g==1)? bkt : bvt;
    __shared__ float emb[384];
    for (int j=tid;j<384;j+=256) emb[j] = temb[bb*384 + j];
    __syncthreads();
    float acc0 = bt[tid], acc1 = bt[tid+256], acc2 = bt[tid+512];
    for (int t=0;t<384;t++){
      float e = emb[t];
      const float* wr = Wt + t*768;
      acc0 += e*wr[tid]; acc1 += e*wr[tid+256]; acc2 += e*wr[tid+512];
    }
    float* dst = Tmat + g*6144 + bb*768;
    float s = (g==0) ? CSC : 1.0f;
    dst[tid] = acc0*s; dst[tid+256] = acc1*s; dst[tid+512] = acc2*s;
  }
}

// ---------------------------------------------------------------------------
// Kernel 3: fused QKV GEMM (A = bf16 patches). Writes:
//   Qs[b][h][s][hd] = (patches@Wqs + bqs) * CSC     (bf16, pre-scaled)
//   K [b][h][s][hd] = ks + kt                        (bf16)
//   V  transposed per head [b][h][hd][s]             (bf16)
// V epilogue routes through LDS so global stores are coalesced 256B runs.
// ---------------------------------------------------------------------------
__global__ __launch_bounds__(256) void qkv_gemm(
    const unsigned short* __restrict__ Pb, const unsigned short* __restrict__ Wb,
    const float* __restrict__ bq, const float* __restrict__ bk,
    const float* __restrict__ bv, const float* __restrict__ Tmat,
    unsigned short* __restrict__ Qs, unsigned short* __restrict__ K,
    unsigned short* __restrict__ V){
  __shared__ unsigned short smem_q[18432];       // a:0..9215, b:9216..18431
  unsigned short* a_lds = smem_q;
  unsigned short* b_lds = smem_q + 9216;
  int g = blockIdx.z;
  int m0 = blockIdx.x*128, n0 = blockIdx.y*128;
  int tid = threadIdx.x, w = tid>>6, lane = tid&63, quad = lane>>4, l16 = lane&15;
  int wr = w>>1, wc = w&1;
  const unsigned short* Wg = Wb + g*589824;
  const float* bias = (g==0)? bq : (g==1)? bk : bv;
  floatx4 acc[4][4];
  #pragma unroll
  for (int i=0;i<4;i++)
    #pragma unroll
    for (int j=0;j<4;j++) acc[i][j] = (floatx4){0.f,0.f,0.f,0.f};

  for (int kt=0; kt<12; kt++){
    int k0 = kt*64;
    __syncthreads();
    #pragma unroll
    for (int i=0;i<4;i++){
      int idx = i*256 + tid;
      int r = idx >> 3, c = (idx & 7) << 3;
      *(uint4*)&a_lds[r*72 + c] = *(const uint4*)&Pb[(m0+r)*768 + k0 + c];
      *(uint4*)&b_lds[r*72 + c] = *(const uint4*)&Wg[(n0+r)*768 + k0 + c];
    }
    __syncthreads();
    #pragma unroll
    for (int ks=0; ks<2; ks++){
      short8 af[4], bf[4];
      #pragma unroll
      for (int mb=0;mb<4;mb++)
        af[mb] = *(const short8*)&a_lds[(wr*64+mb*16+l16)*72 + ks*32 + quad*8];
      #pragma unroll
      for (int nb=0;nb<4;nb++)
        bf[nb] = *(const short8*)&b_lds[(wc*64+nb*16+l16)*72 + ks*32 + quad*8];
      #pragma unroll
      for (int mb=0;mb<4;mb++)
        #pragma unroll
        for (int nb=0;nb<4;nb++)
          acc[mb][nb] = mfma16(af[mb], bf[nb], acc[mb][nb]);
    }
  }
  if (g < 2){
    #pragma unroll
    for (int mb=0;mb<4;mb++)
    #pragma unroll
    for (int nb=0;nb<4;nb++)
    #pragma unroll
    for (int reg=0;reg<4;reg++){
      int m = m0 + wr*64 + mb*16 + quad*4 + reg;
      int n = n0 + wc*64 + nb*16 + l16;
      int bb = m >> 10, s = m & 1023, h = n >> 6, hd = n & 63;
      float v = acc[mb][nb][reg] + bias[n];
      int base = (bb*12 + h) << 16;
      if (g == 0){
        Qs[base + (s<<6) + hd] = f2b(v * CSC);
      } else {
        float tadd = Tmat[6144 + bb*768 + n];
        K[base + (s<<6) + hd] = f2b(v + tadd);
      }
    }
  } else {
    // V: write C-tile transposed into LDS (stride 136), then coalesced store
    __syncthreads();     // main-loop LDS reads complete
    int bb = m0 >> 10;
    #pragma unroll
    for (int mb=0;mb<4;mb++)
    #pragma unroll
    for (int nb=0;nb<4;nb++)
    #pragma unroll
    for (int reg=0;reg<4;reg++){
      int ml = wr*64 + mb*16 + quad*4 + reg;
      int nl = wc*64 + nb*16 + l16;
      int n = n0 + nl;
      float v = acc[mb][nb][reg] + bias[n] + Tmat[12288 + bb*768 + n];
      smem_q[nl*136 + ml] = f2b(v);
    }
    __syncthreads();
    int s0 = m0 & 1023;
    #pragma unroll
    for (int i=0;i<8;i++){
      int idx = i*256 + tid;
      int r = idx >> 4, c8 = (idx & 15) << 3;   // r: n_local, c8: m_local
      int n = n0 + r, h = n >> 6, hd = n & 63;
      int base = (bb*12 + h) << 16;
      *(uint4*)&V[base + (hd<<10) + s0 + c8] = *(const uint4*)&smem_q[r*136 + c8];
    }
  }
}

// ---------------------------------------------------------------------------
// Kernel 4: flash attention w/ skewed relative bias — R5's proven 167 µs
// configuration, verbatim. Block = 256 threads (4 waves), q-PAIR (A=q0,
// B=q0+64) per k-tile; one K/V staging + 2 barriers feed 2x compute.
// Grid 768 = 3 blocks/CU, single round. Band & P share ONE wave-private
// 16x88 region (strictly sequential in-wave reuse). K/V register prefetch.
// LDS = 29696 B. (R8 lesson: do NOT dedup PV/vf or re-layout the band —
// the extra live state spills the q-fragments and costs +60% wall time.)
// ---------------------------------------------------------------------------
__global__ __launch_bounds__(256, 3) void attn_kernel(
    const unsigned short* __restrict__ Qsp, const unsigned short* __restrict__ Kp,
    const unsigned short* __restrict__ Vtp, const unsigned short* __restrict__ Erb,
    const float* __restrict__ Tq, float* __restrict__ out){
  __shared__ __align__(16) char smem[29696];
  unsigned short* k_lds  = (unsigned short*)smem;            // 64x72
  unsigned short* v_lds  = (unsigned short*)(smem + 9216);   // 64x72 (vT [hd][key])
  unsigned short* pw_all = (unsigned short*)(smem + 18432);  // 4 x (16x88)

  int tid = threadIdx.x, w = tid>>6, lane = tid&63, quad = lane>>4, l16 = lane&15;
  unsigned short* pw = pw_all + w*1408;    // this wave's 16x88 region
  int q0 = blockIdx.x*128, h = blockIdx.y, b = blockIdx.z;
  int hb = (b*12 + h) << 16;
  const unsigned short* Qsh = Qsp + hb;
  const unsigned short* Kh  = Kp  + hb;
  const unsigned short* Vh  = Vtp + hb;
  const float* tqv = Tq + b*768 + h*64;    // pre-scaled by CSC

  int frow = w*16 + l16;
  short8 qf[2][2], qlo[2][2], qhi[2][2];   // [sub][ks]
  #pragma unroll
  for (int sub=0; sub<2; sub++){
    int qrow = q0 + sub*64 + frow;
    int qrow1 = (qrow < 1023) ? qrow+1 : 1023;
    #pragma unroll
    for (int ks=0; ks<2; ks++){
      int c = ks*32 + quad*8;
      qlo[sub][ks] = *(const short8*)&Qsh[(qrow <<6) + c];
      qhi[sub][ks] = *(const short8*)&Qsh[(qrow1<<6) + c];
      float4 t0 = *(const float4*)&tqv[c];
      float4 t1 = *(const float4*)&tqv[c+4];
      short8 qq;
      qq[0]=(short)f2b(b2f((unsigned short)qlo[sub][ks][0])+t0.x);
      qq[1]=(short)f2b(b2f((unsigned short)qlo[sub][ks][1])+t0.y);
      qq[2]=(short)f2b(b2f((unsigned short)qlo[sub][ks][2])+t0.z);
      qq[3]=(short)f2b(b2f((unsigned short)qlo[sub][ks][3])+t0.w);
      qq[4]=(short)f2b(b2f((unsigned short)qlo[sub][ks][4])+t1.x);
      qq[5]=(short)f2b(b2f((unsigned short)qlo[sub][ks][5])+t1.y);
      qq[6]=(short)f2b(b2f((unsigned short)qlo[sub][ks][6])+t1.z);
      qq[7]=(short)f2b(b2f((unsigned short)qlo[sub][ks][7])+t1.w);
      qf[sub][ks] = qq;
    }
  }

  float lpart[2][4] = {{0.f,0.f,0.f,0.f},{0.f,0.f,0.f,0.f}};
  floatx4 o_acc[2][4];
  #pragma unroll
  for (int sub=0;sub<2;sub++)
    #pragma unroll
    for (int ob=0;ob<4;ob++) o_acc[sub][ob] = (floatx4){0.f,0.f,0.f,0.f};

  int ql = quad*4;           // + reg = within-wave q row
  int ub_lo = 3 - w;         // wave-w band blocks [3-w, 7-w]

  // K/V staging addressing: thread covers rows sr, sr+32 (col chunk scc)
  int sr = tid>>3, scc = (tid&7)<<3;
  uint4 kr0, kr1, vr0, vr1;
  kr0 = *(const uint4*)&Kh[(sr<<6) + scc];
  kr1 = *(const uint4*)&Kh[((sr+32)<<6) + scc];
  vr0 = *(const uint4*)&Vh[(sr<<10) + scc];
  vr1 = *(const uint4*)&Vh[((sr+32)<<10) + scc];

  for (int kt=0; kt<16; kt++){
    int k0 = kt*64;
    __syncthreads();                       // all waves done reading k/v
    *(uint4*)&k_lds[sr*72 + scc]      = kr0;
    *(uint4*)&k_lds[(sr+32)*72 + scc] = kr1;
    *(uint4*)&v_lds[sr*72 + scc]      = vr0;
    *(uint4*)&v_lds[(sr+32)*72 + scc] = vr1;
    __syncthreads();
    // prefetch next k-tile (clamped re-load of tile 15 on last iter)
    int k0n = (kt < 15) ? k0 + 64 : k0;
    kr0 = *(const uint4*)&Kh[((k0n+sr)<<6) + scc];
    kr1 = *(const uint4*)&Kh[((k0n+sr+32)<<6) + scc];
    vr0 = *(const uint4*)&Vh[(sr<<10) + k0n + scc];
    vr1 = *(const uint4*)&Vh[((sr+32)<<10) + k0n + scc];

    // ---- QK^T for both sub-tiles, sharing kf fragment reads ----
    floatx4 sc[2][4];
    #pragma unroll
    for (int nb=0;nb<4;nb++){
      sc[0][nb] = (floatx4){0.f,0.f,0.f,0.f};
      sc[1][nb] = (floatx4){0.f,0.f,0.f,0.f};
      #pragma unroll
      for (int ks=0;ks<2;ks++){
        short8 kf = *(const short8*)&k_lds[(nb*16+l16)*72 + ks*32 + quad*8];
        sc[0][nb] = mfma16(qf[0][ks], kf, sc[0][nb]);
        sc[1][nb] = mfma16(qf[1][ks], kf, sc[1][nb]);
      }
    }

    #pragma unroll
    for (int sub=0; sub<2; sub++){
      int diag = k0 - q0 - sub*64;
      bool needL = (diag <= 0), needU = (diag >= 0);
      bool needSel = (diag == 0) || (diag == 64);
      for (int pass=0; pass<2; pass++){
        if ((pass==0 && !needL) || (pass==1 && !needU)) continue;
        int tbase = (pass==0) ? (960 + diag) : (diag - 65);
        const short8* af = (pass==0) ? qlo[sub] : qhi[sub];
        // band GEMM: 5 ub blocks per wave, Er B-frags direct from global
        #pragma unroll
        for (int lb=0; lb<5; lb++){
          int ub = ub_lo + lb;
          int t = tbase + ub*16 + l16;
          t = (t < 0) ? 0 : (t > 1023 ? 1023 : t);
          floatx4 pa = (floatx4){0.f,0.f,0.f,0.f};
          #pragma unroll
          for (int ks=0;ks<2;ks++){
            short8 ef = *(const short8*)&Erb[(t<<6) + ks*32 + quad*8];
            pa = mfma16(af[ks], ef, pa);
          }
          #pragma unroll
          for (int reg=0;reg<4;reg++)
            pw[(ql + reg)*88 + lb*16 + l16] = f2b(pa[reg]);
        }
        // gather-add (wave-private; in-wave DS ordering)
        #pragma unroll
        for (int nb=0;nb<4;nb++)
        #pragma unroll
        for (int reg=0;reg<4;reg++){
          int qlr = ql + reg;
          int ki = nb*16 + l16;
          float bv = b2f(pw[qlr*88 + 15 + ki - qlr]);
          if (needSel){
            int kq = diag + ki - (w*16 + qlr);
            bool sel = (pass==0) ? (kq <= 0) : (kq >= 2);
            bv = sel ? bv : 0.f;
          }
          sc[sub][nb][reg] += bv;
        }
      }
      // ---- fixed-base softmax: p = 2^sc (scale folded into Q/Qs) ----
      #pragma unroll
      for (int nb=0;nb<4;nb++)
      #pragma unroll
      for (int reg=0;reg<4;reg++){
        float p = __builtin_amdgcn_exp2f(sc[sub][nb][reg]);
        lpart[sub][reg] += p;
        pw[(ql + reg)*88 + nb*16 + l16] = f2b(p);
      }
      short8 pf[2];
      #pragma unroll
      for (int ks=0;ks<2;ks++)
        pf[ks] = *(const short8*)&pw[l16*88 + ks*32 + quad*8];
      #pragma unroll
      for (int ob=0;ob<4;ob++){
        #pragma unroll
        for (int ks=0;ks<2;ks++){
          short8 vf = *(const short8*)&v_lds[(ob*16+l16)*72 + ks*32 + quad*8];
          o_acc[sub][ob] = mfma16(pf[ks], vf, o_acc[sub][ob]);
        }
      }
    }
  }
  // final row-sum reduce (deferred; no per-tile rescale happened)
  #pragma unroll
  for (int sub=0;sub<2;sub++){
    float rl[4];
    #pragma unroll
    for (int reg=0;reg<4;reg++){
      float l = lpart[sub][reg];
      #pragma unroll
      for (int off=1; off<16; off<<=1) l += __shfl_xor(l, off);
      rl[reg] = __builtin_amdgcn_rcpf(l);
    }
    #pragma unroll
    for (int ob=0;ob<4;ob++)
    #pragma unroll
    for (int reg=0;reg<4;reg++){
      int s = q0 + sub*64 + w*16 + quad*4 + reg;
      out[((b<<10) + s)*768 + (h<<6) + ob*16 + l16] = o_acc[sub][ob][reg] * rl[reg];
    }
  }
}

// ---------------------------------------------------------------------------
extern "C" void kernel_launch(void* const* d_in, const int* in_sizes, int n_in,
                              void* d_out, int out_size, void* d_ws, size_t ws_size,
                              hipStream_t stream) {
  const float* patches  = (const float*)d_in[0];
  const float* time_emb = (const float*)d_in[1];
  const float* Wqs = (const float*)d_in[2];  const float* bqs = (const float*)d_in[3];
  const float* Wks = (const float*)d_in[4];  const float* bks = (const float*)d_in[5];
  const float* Wvs = (const float*)d_in[6];  const float* bvs = (const float*)d_in[7];
  const float* Wqt = (const float*)d_in[8];  const float* bqt = (const float*)d_in[9];
  const float* Wkt = (const float*)d_in[10]; const float* bkt = (const float*)d_in[11];
  const float* Wvt = (const float*)d_in[12]; const float* bvt = (const float*)d_in[13];
  const float* Er  = (const float*)d_in[14];

  unsigned short* Qsp  = (unsigned short*)d_ws;     // 6291456 (bf16, pre-scaled)
  unsigned short* Kp   = Qsp + 6291456;
  unsigned short* Vp   = Kp  + 6291456;             // transposed per head [hd][s]
  unsigned short* Wbp  = Vp  + 6291456;             // 3*589824, [g][n][k]
  unsigned short* Erbp = Wbp + 1769472;             // 65536
  unsigned short* Pbp  = Erbp + 65536;              // 6291456 (patches bf16)
  float*          Tmat = (float*)(Pbp + 6291456);   // 3*8*768 fp32 (g0 * CSC)

  float* out = (float*)d_out;

  hipLaunchKernelGGL(convert_kernel, dim3(3128), dim3(256), 0, stream,
                     patches, Er, time_emb, Wqt, bqt, Wkt, bkt, Wvt, bvt,
                     Pbp, Erbp, Tmat);
  hipLaunchKernelGGL(transpose_w, dim3(12,12,3), dim3(256), 0, stream,
                     Wqs, Wks, Wvs, Wbp);
  hipLaunchKernelGGL(qkv_gemm, dim3(64,6,3), dim3(256), 0, stream,
                     Pbp, Wbp, bqs, bks, bvs, Tmat, Qsp, Kp, Vp);
  hipLaunchKernelGGL(attn_kernel, dim3(8,12,8), dim3(256), 0, stream,
                     Qsp, Kp, Vp, Erbp, Tmat, out);
}